// Round 19
// baseline (686.424 us; speedup 1.0000x reference)
//
#include <hip/hip_runtime.h>

#define N_USERS 200000
#define N_ITEMS 100000
#define NN      300000        // N_USERS + N_ITEMS
#define DIM     64
#define N_EDGES 9600000
#define BATCH   16384
#define BSH     9             // 512 rows per bucket
#define NBK     586           // ceil(NN / 512)
#define CHUNK2  2048          // edges per bin_sort block (5 blocks/CU)
#define CAP     17408         // fixed bucket capacity: mean 16384 + 8 sigma

// ---------------- bf16 helpers (RNE) ----------------
__device__ __forceinline__ unsigned short f2bf(float f) {
    unsigned b = __float_as_uint(f);
    return (unsigned short)((b + 0x7FFF + ((b >> 16) & 1)) >> 16);
}
__device__ __forceinline__ float bf2f(unsigned short u) {
    return __uint_as_float((unsigned)u << 16);
}

// ---------------- E0 -> bf16 concat table ----------------
__global__ void to_bf16(const float* __restrict__ ue, const float* __restrict__ ie,
                        unsigned short* __restrict__ E) {
    const size_t nU = (size_t)N_USERS * DIM / 4;
    const size_t nT = (size_t)NN * DIM / 4;
    const float4* u4 = (const float4*)ue;
    const float4* i4 = (const float4*)ie;
    ushort4* E4 = (ushort4*)E;
    size_t stride = (size_t)gridDim.x * blockDim.x;
    for (size_t k = (size_t)blockIdx.x * blockDim.x + threadIdx.x; k < nT; k += stride) {
        float4 v = (k < nU) ? u4[k] : i4[k - nU];
        ushort4 o;
        o.x = f2bf(v.x); o.y = f2bf(v.y); o.z = f2bf(v.z); o.w = f2bf(v.w);
        E4[k] = o;
    }
}

// ---------------- pass 1: per-block counting sort into fixed-capacity 512-row buckets ----------------
// CHUNK=2048 + dstb[] (no binary search): ~31.6 KB LDS -> 5 blocks/CU.
__global__ __launch_bounds__(256) void bin_sort(const int* __restrict__ rows,
                                                const int* __restrict__ cols,
                                                const float* __restrict__ vals,
                                                int* __restrict__ gfill,
                                                int2* __restrict__ estage) {
    __shared__ int  hist[NBK + 1];   // counts -> local exclusive starts
    __shared__ int  gbase[NBK];
    __shared__ int  rankc[NBK];
    __shared__ int2 st[CHUNK2];
    __shared__ int  dstb[CHUNK2];
    int* sc = (int*)st;              // scan scratch (dead before staging)

    int tid = threadIdx.x;
    int e0 = blockIdx.x * CHUNK2;
    int e1 = min(e0 + CHUNK2, N_EDGES);
    int n  = e1 - e0;

    for (int i = tid; i <= NBK; i += 256) hist[i] = 0;
    __syncthreads();

    for (int e = e0 + tid; e < e1; e += 256)
        atomicAdd(&hist[rows[e] >> BSH], 1);
    __syncthreads();

    for (int i = tid; i < NBK; i += 256) sc[i] = hist[i];
    __syncthreads();

    // inclusive Hillis-Steele scan over NBK entries (256 threads own 3 slots each)
    for (int off = 1; off < NBK; off <<= 1) {
        int a[3];
        #pragma unroll
        for (int k = 0; k < 3; ++k) {
            int i = tid + (k << 8);
            a[k] = (i < NBK && i >= off) ? sc[i - off] : 0;
        }
        __syncthreads();
        #pragma unroll
        for (int k = 0; k < 3; ++k) {
            int i = tid + (k << 8);
            if (i < NBK && i >= off) sc[i] += a[k];
        }
        __syncthreads();
    }

    for (int b = tid; b < NBK; b += 256) {
        int cb = hist[b];
        hist[b] = sc[b] - cb;                     // local exclusive start
        gbase[b] = b * CAP + (cb ? atomicAdd(&gfill[b], cb) : 0);
        rankc[b] = 0;
    }
    __syncthreads();                              // sc dead from here

    // rank + reorder into LDS (bucket-grouped order), record destination
    for (int e = e0 + tid; e < e1; e += 256) {
        int r = rows[e];
        int c = cols[e];
        float v = vals[e];
        int b = r >> BSH;
        int lr = atomicAdd(&rankc[b], 1);
        int lpos = hist[b] + lr;
        st[lpos]   = make_int2(((r & 511) << 19) | c, __float_as_int(v));
        dstb[lpos] = gbase[b] + lr;
    }
    __syncthreads();

    // flush: bucket-grouped LDS order -> consecutive global addresses per run
    for (int i = tid; i < n; i += 256)
        estage[dstb[i]] = st[i];
}

// ---------------- pass 2: one block per 512-row bucket; edges staged ONCE in LDS ----------------
// rp has one extra slot per bucket: spmm indexes rp[row + (row>>BSH)].
__global__ __launch_bounds__(1024) void row_scatter(const int* __restrict__ gfill,
                                                    const int2* __restrict__ estage,
                                                    int2* __restrict__ epack,
                                                    int* __restrict__ rp) {
    __shared__ int2 st[CAP];         // 139.3 KB static LDS (proven working r17/r18)
    __shared__ int  lcnt[512];
    __shared__ int  s[512];
    int b = blockIdx.x;
    int r0 = b << BSH;
    int nr = min(512, NN - r0);
    int tid = threadIdx.x;
    int ebeg = b * CAP;
    int cnt  = gfill[b];

    for (int e = tid; e < cnt; e += 1024) st[e] = estage[ebeg + e];
    if (tid < 512) lcnt[tid] = 0;
    __syncthreads();

    for (int e = tid; e < cnt; e += 1024)
        atomicAdd(&lcnt[((unsigned)st[e].x) >> 19], 1);
    __syncthreads();

    int x = 0;
    if (tid < 512) { x = lcnt[tid]; s[tid] = x; }
    __syncthreads();
    for (int off = 1; off < 512; off <<= 1) {
        int t = 0;
        if (tid < 512 && tid >= off) t = s[tid - off];
        __syncthreads();
        if (tid < 512 && tid >= off) s[tid] += t;
        __syncthreads();
    }
    if (tid < nr) rp[r0 + b + tid] = ebeg + s[tid] - x;
    if (tid == 0) rp[r0 + b + nr] = ebeg + cnt;   // bucket end slot
    if (tid < 512) lcnt[tid] = ebeg + s[tid] - x; // reuse as ticket
    __syncthreads();

    for (int e = tid; e < cnt; e += 1024) {
        int2 ed = st[e];
        int rl = ((unsigned)ed.x) >> 19;
        int pos = atomicAdd(&lcnt[rl], 1);
        epack[pos] = make_int2(ed.x & 0x7FFFF, ed.y);
    }
}

// ---------------- row-dot: 8-wide unroll, nt edge-stream loads, bf16 gather ----------------
__device__ __forceinline__ float row_dot(const int2* __restrict__ ep, int beg, int end,
                                         const unsigned short* __restrict__ E, int lane) {
    const long long* epl = (const long long*)ep;
    float acc = 0.f;
    int j = beg;
    int jend8 = beg + ((end - beg) & ~7);
    for (; j < jend8; j += 8) {
        long long d[8];
        #pragma unroll
        for (int k = 0; k < 8; ++k) d[k] = __builtin_nontemporal_load(&epl[j + k]);
        float x[8];
        #pragma unroll
        for (int k = 0; k < 8; ++k)
            x[k] = bf2f(E[(size_t)(int)(d[k] & 0x7FFFF) * DIM + lane]);
        #pragma unroll
        for (int k = 0; k < 8; ++k)
            acc = __builtin_fmaf(__int_as_float((int)(d[k] >> 32)), x[k], acc);
    }
    if (j + 4 <= end) {
        long long d[4];
        #pragma unroll
        for (int k = 0; k < 4; ++k) d[k] = __builtin_nontemporal_load(&epl[j + k]);
        float x[4];
        #pragma unroll
        for (int k = 0; k < 4; ++k)
            x[k] = bf2f(E[(size_t)(int)(d[k] & 0x7FFFF) * DIM + lane]);
        #pragma unroll
        for (int k = 0; k < 4; ++k)
            acc = __builtin_fmaf(__int_as_float((int)(d[k] >> 32)), x[k], acc);
        j += 4;
    }
    for (; j < end; ++j) {
        long long d = __builtin_nontemporal_load(&epl[j]);
        acc = __builtin_fmaf(__int_as_float((int)(d >> 32)),
                             bf2f(E[(size_t)(int)(d & 0x7FFFF) * DIM + lane]), acc);
    }
    return acc;
}

// ---------------- SpMM: one wave per row, lane = dim, bf16 in/out ----------------
__global__ void spmm_csr(const int* __restrict__ rp, const int2* __restrict__ ep,
                         const unsigned short* __restrict__ Ein,
                         unsigned short* __restrict__ Eout) {
    int lane = threadIdx.x & 63;
    int w = (int)((blockIdx.x * (size_t)blockDim.x + threadIdx.x) >> 6);
    int row = __builtin_amdgcn_readfirstlane(w);
    if (row >= NN) return;
    int idx = row + (row >> BSH);
    int beg = rp[idx];
    int end = rp[idx + 1];
    float acc = row_dot(ep, beg, end, Ein, lane);
    __builtin_nontemporal_store(f2bf(acc), &Eout[(size_t)row * DIM + lane]);
}

// ---------------- layer 3: SpMM only at the 2*BATCH target rows, fused acc ----------------
__global__ void spmm_target(const int* __restrict__ rp, const int2* __restrict__ ep,
                            const unsigned short* __restrict__ Ein,
                            const int* __restrict__ U, const int* __restrict__ I,
                            float* __restrict__ accU, float* __restrict__ accI) {
    int lane = threadIdx.x & 63;
    int w = (int)((blockIdx.x * (size_t)blockDim.x + threadIdx.x) >> 6);
    if (w >= 2 * BATCH) return;
    int row;
    float* accp;
    if (w < BATCH) { row = U[w];                   accp = accU + (size_t)w * DIM; }
    else           { row = N_USERS + I[w - BATCH]; accp = accI + (size_t)(w - BATCH) * DIM; }
    row = __builtin_amdgcn_readfirstlane(row);
    int idx = row + (row >> BSH);
    int beg = rp[idx];
    int end = rp[idx + 1];
    float acc = row_dot(ep, beg, end, Ein, lane);
    accp[lane] += acc;
}

// ---------------- acc at the 2*BATCH target rows ----------------
__global__ void acc_init(const float* __restrict__ ue, const float* __restrict__ ie,
                         const int* __restrict__ U, const int* __restrict__ I,
                         float* __restrict__ accU, float* __restrict__ accI) {
    int t = blockIdx.x * blockDim.x + threadIdx.x;
    int b = t >> 6, d = t & 63;
    accU[t] = ue[(size_t)U[b] * DIM + d];
    accI[t] = ie[(size_t)I[b] * DIM + d];
}

__global__ void acc_add(const unsigned short* __restrict__ E, const int* __restrict__ U,
                        const int* __restrict__ I, float* __restrict__ accU,
                        float* __restrict__ accI) {
    int t = blockIdx.x * blockDim.x + threadIdx.x;
    int b = t >> 6, d = t & 63;
    accU[t] += bf2f(E[(size_t)U[b] * DIM + d]);
    accI[t] += bf2f(E[(size_t)(N_USERS + I[b]) * DIM + d]);
}

// ---------------- final: out[b] = dot(accU[b], accI[b]) / 16 ----------------
__global__ void dot_out(const float* __restrict__ accU, const float* __restrict__ accI,
                        float* __restrict__ out) {
    int t = blockIdx.x * blockDim.x + threadIdx.x;
    int b = t >> 6, lane = threadIdx.x & 63;
    float p = accU[t] * accI[t];
    #pragma unroll
    for (int off = 32; off; off >>= 1) p += __shfl_xor(p, off, 64);
    if (lane == 0) out[b] = p * (1.0f / 16.0f);
}

extern "C" void kernel_launch(void* const* d_in, const int* in_sizes, int n_in,
                              void* d_out, int out_size, void* d_ws, size_t ws_size,
                              hipStream_t stream) {
    const float* ue   = (const float*)d_in[0];
    const float* ie   = (const float*)d_in[1];
    const float* vals = (const float*)d_in[2];
    const int*   rows = (const int*)d_in[3];
    const int*   cols = (const int*)d_in[4];
    const int*   U    = (const int*)d_in[5];
    const int*   I    = (const int*)d_in[6];
    float* out = (float*)d_out;

    char* ws = (char*)d_ws;
    const size_t EPbytes = (size_t)NBK * CAP * sizeof(int2);          // 81.6 MB (CAP-strided)
    const size_t EBbytes = (size_t)NN * DIM * sizeof(unsigned short); // 38.4 MB
    const size_t ACbytes = (size_t)BATCH * DIM * sizeof(float);       // 4.2 MB
    const size_t RPbytes = ((size_t)(NN + NBK + 1) * sizeof(int) + 255) & ~(size_t)255;
    const size_t NBbytes = (((size_t)(NBK + 1) * sizeof(int)) + 255) & ~(size_t)255;

    size_t off = 0;
    int2*  epack  = (int2*)(ws + off);                   off += EPbytes;
    char*  region2 = ws + off;                           off += EPbytes; // estage | Ebf_a+Ebf_b
    float* accU   = (float*)(ws + off); off += ACbytes;
    float* accI   = (float*)(ws + off); off += ACbytes;
    int*   rp     = (int*)(ws + off);   off += RPbytes;
    int*   gfill  = (int*)(ws + off);   off += NBbytes;

    // estage (build phase) aliases the Ebf region (layer phase) — disjoint lifetimes
    int2* estage = (int2*)region2;
    unsigned short* Ebf_a = (unsigned short*)region2;
    unsigned short* Ebf_b = (unsigned short*)(region2 + EBbytes);

    const int nBinBlocks = (N_EDGES + CHUNK2 - 1) / CHUNK2;           // 4688

    // --- build CSR (fixed-capacity 512-row buckets) ---
    hipMemsetAsync(gfill, 0, (size_t)(NBK + 1) * sizeof(int), stream);
    bin_sort<<<nBinBlocks, 256, 0, stream>>>(rows, cols, vals, gfill, estage);
    row_scatter<<<NBK, 1024, 0, stream>>>(gfill, estage, epack, rp);

    // --- bf16 embedding table (after estage is dead) + exact-f32 E0 term ---
    to_bf16<<<2048, 256, 0, stream>>>(ue, ie, Ebf_a);
    acc_init<<<BATCH * DIM / 256, 256, 0, stream>>>(ue, ie, U, I, accU, accI);

    const int spmmBlocks = (NN * 64 + 255) / 256;                     // 1 wave per row

    // layer 1: Ebf_a -> Ebf_b
    spmm_csr<<<spmmBlocks, 256, 0, stream>>>(rp, epack, Ebf_a, Ebf_b);
    acc_add<<<BATCH * DIM / 256, 256, 0, stream>>>(Ebf_b, U, I, accU, accI);

    // layer 2: Ebf_b -> Ebf_a
    spmm_csr<<<spmmBlocks, 256, 0, stream>>>(rp, epack, Ebf_b, Ebf_a);
    acc_add<<<BATCH * DIM / 256, 256, 0, stream>>>(Ebf_a, U, I, accU, accI);

    // layer 3: only at target rows, fused accumulate
    spmm_target<<<2 * BATCH * 64 / 256, 256, 0, stream>>>(rp, epack, Ebf_a, U, I, accU, accI);

    dot_out<<<BATCH / 4, 256, 0, stream>>>(accU, accI, out);
}

// Round 20
// 672.349 us; speedup vs baseline: 1.0209x; 1.0209x over previous
//
#include <hip/hip_runtime.h>

#define N_USERS 200000
#define N_ITEMS 100000
#define NN      300000        // N_USERS + N_ITEMS
#define DIM     64
#define N_EDGES 9600000
#define BATCH   16384
#define BSH     9             // 512 rows per bucket
#define NBK     586           // ceil(NN / 512)
#define CHUNK2  4096          // edges per bin_sort block
#define CAP     17408         // fixed bucket capacity: mean 16384 + 8 sigma

// ---------------- bf16 helpers (RNE) ----------------
__device__ __forceinline__ unsigned short f2bf(float f) {
    unsigned b = __float_as_uint(f);
    return (unsigned short)((b + 0x7FFF + ((b >> 16) & 1)) >> 16);
}
__device__ __forceinline__ float bf2f(unsigned short u) {
    return __uint_as_float((unsigned)u << 16);
}

// ---------------- E0 -> bf16 concat table ----------------
__global__ void to_bf16(const float* __restrict__ ue, const float* __restrict__ ie,
                        unsigned short* __restrict__ E) {
    const size_t nU = (size_t)N_USERS * DIM / 4;
    const size_t nT = (size_t)NN * DIM / 4;
    const float4* u4 = (const float4*)ue;
    const float4* i4 = (const float4*)ie;
    ushort4* E4 = (ushort4*)E;
    size_t stride = (size_t)gridDim.x * blockDim.x;
    for (size_t k = (size_t)blockIdx.x * blockDim.x + threadIdx.x; k < nT; k += stride) {
        float4 v = (k < nU) ? u4[k] : i4[k - nU];
        ushort4 o;
        o.x = f2bf(v.x); o.y = f2bf(v.y); o.z = f2bf(v.z); o.w = f2bf(v.w);
        E4[k] = o;
    }
}

// ---------------- pass 1: per-block counting sort into fixed-capacity 512-row buckets ----------------
// Scan scratch aliases st[] (dead until staging) -> tables only ~7 KB, 39 KB LDS total.
__global__ __launch_bounds__(256) void bin_sort(const int* __restrict__ rows,
                                                const int* __restrict__ cols,
                                                const float* __restrict__ vals,
                                                int* __restrict__ gfill,
                                                int2* __restrict__ estage) {
    __shared__ int  hist[NBK + 1];   // counts -> local exclusive starts (+ sentinel)
    __shared__ int  gbase[NBK];
    __shared__ int  rankc[NBK];
    __shared__ int2 st[CHUNK2];
    int* sc = (int*)st;              // scan scratch (dead before staging)

    int tid = threadIdx.x;
    int e0 = blockIdx.x * CHUNK2;
    int e1 = min(e0 + CHUNK2, N_EDGES);
    int n  = e1 - e0;

    for (int i = tid; i <= NBK; i += 256) hist[i] = 0;
    __syncthreads();

    for (int e = e0 + tid; e < e1; e += 256)
        atomicAdd(&hist[rows[e] >> BSH], 1);
    __syncthreads();

    for (int i = tid; i < NBK; i += 256) sc[i] = hist[i];
    __syncthreads();

    // inclusive Hillis-Steele scan over NBK entries (256 threads own 3 slots each)
    for (int off = 1; off < NBK; off <<= 1) {
        int a[3];
        #pragma unroll
        for (int k = 0; k < 3; ++k) {
            int i = tid + (k << 8);
            a[k] = (i < NBK && i >= off) ? sc[i - off] : 0;
        }
        __syncthreads();
        #pragma unroll
        for (int k = 0; k < 3; ++k) {
            int i = tid + (k << 8);
            if (i < NBK && i >= off) sc[i] += a[k];
        }
        __syncthreads();
    }

    for (int b = tid; b < NBK; b += 256) {
        int cb = hist[b];
        hist[b] = sc[b] - cb;                     // local exclusive start
        gbase[b] = b * CAP + (cb ? atomicAdd(&gfill[b], cb) : 0);
        rankc[b] = 0;
    }
    if (tid == 0) hist[NBK] = CHUNK2 + 1;         // sentinel > any i
    __syncthreads();                              // sc dead from here

    // rank + reorder into LDS (bucket-grouped order)
    for (int e = e0 + tid; e < e1; e += 256) {
        int r = rows[e];
        int c = cols[e];
        float v = vals[e];
        int b = r >> BSH;
        int lr = atomicAdd(&rankc[b], 1);
        st[hist[b] + lr] = make_int2(((r & 511) << 19) | c, __float_as_int(v));
    }
    __syncthreads();

    // flush: bucket of slot i via binary search (last b with hist[b] <= i)
    for (int i = tid; i < n; i += 256) {
        int lo = 0, hi = NBK;
        while (hi - lo > 1) {
            int mid = (lo + hi) >> 1;
            if (hist[mid] <= i) lo = mid; else hi = mid;
        }
        estage[gbase[lo] + (i - hist[lo])] = st[i];
    }
}

// ---------------- pass 2: one block per 512-row bucket; edges staged ONCE in LDS ----------------
// rp has one extra slot per bucket: spmm indexes rp[row + (row>>BSH)].
__global__ __launch_bounds__(1024) void row_scatter(const int* __restrict__ gfill,
                                                    const int2* __restrict__ estage,
                                                    int2* __restrict__ epack,
                                                    int* __restrict__ rp) {
    __shared__ int2 st[CAP];         // 139.3 KB static LDS (proven working r17/r18)
    __shared__ int  lcnt[512];
    __shared__ int  s[512];
    int b = blockIdx.x;
    int r0 = b << BSH;
    int nr = min(512, NN - r0);
    int tid = threadIdx.x;
    int ebeg = b * CAP;
    int cnt  = gfill[b];

    for (int e = tid; e < cnt; e += 1024) st[e] = estage[ebeg + e];
    if (tid < 512) lcnt[tid] = 0;
    __syncthreads();

    for (int e = tid; e < cnt; e += 1024)
        atomicAdd(&lcnt[((unsigned)st[e].x) >> 19], 1);
    __syncthreads();

    int x = 0;
    if (tid < 512) { x = lcnt[tid]; s[tid] = x; }
    __syncthreads();
    for (int off = 1; off < 512; off <<= 1) {
        int t = 0;
        if (tid < 512 && tid >= off) t = s[tid - off];
        __syncthreads();
        if (tid < 512 && tid >= off) s[tid] += t;
        __syncthreads();
    }
    if (tid < nr) rp[r0 + b + tid] = ebeg + s[tid] - x;
    if (tid == 0) rp[r0 + b + nr] = ebeg + cnt;   // bucket end slot
    if (tid < 512) lcnt[tid] = ebeg + s[tid] - x; // reuse as ticket
    __syncthreads();

    for (int e = tid; e < cnt; e += 1024) {
        int2 ed = st[e];
        int rl = ((unsigned)ed.x) >> 19;
        int pos = atomicAdd(&lcnt[rl], 1);
        epack[pos] = make_int2(ed.x & 0x7FFFF, ed.y);
    }
}

// ---------------- row-dot: 8-wide unroll, nt edge-stream loads, bf16 gather ----------------
__device__ __forceinline__ float row_dot(const int2* __restrict__ ep, int beg, int end,
                                         const unsigned short* __restrict__ E, int lane) {
    const long long* epl = (const long long*)ep;
    float acc = 0.f;
    int j = beg;
    int jend8 = beg + ((end - beg) & ~7);
    for (; j < jend8; j += 8) {
        long long d[8];
        #pragma unroll
        for (int k = 0; k < 8; ++k) d[k] = __builtin_nontemporal_load(&epl[j + k]);
        float x[8];
        #pragma unroll
        for (int k = 0; k < 8; ++k)
            x[k] = bf2f(E[(size_t)(int)(d[k] & 0x7FFFF) * DIM + lane]);
        #pragma unroll
        for (int k = 0; k < 8; ++k)
            acc = __builtin_fmaf(__int_as_float((int)(d[k] >> 32)), x[k], acc);
    }
    if (j + 4 <= end) {
        long long d[4];
        #pragma unroll
        for (int k = 0; k < 4; ++k) d[k] = __builtin_nontemporal_load(&epl[j + k]);
        float x[4];
        #pragma unroll
        for (int k = 0; k < 4; ++k)
            x[k] = bf2f(E[(size_t)(int)(d[k] & 0x7FFFF) * DIM + lane]);
        #pragma unroll
        for (int k = 0; k < 4; ++k)
            acc = __builtin_fmaf(__int_as_float((int)(d[k] >> 32)), x[k], acc);
        j += 4;
    }
    for (; j < end; ++j) {
        long long d = __builtin_nontemporal_load(&epl[j]);
        acc = __builtin_fmaf(__int_as_float((int)(d >> 32)),
                             bf2f(E[(size_t)(int)(d & 0x7FFFF) * DIM + lane]), acc);
    }
    return acc;
}

// ---------------- SpMM: one wave per row, lane = dim, bf16 in/out ----------------
__global__ void spmm_csr(const int* __restrict__ rp, const int2* __restrict__ ep,
                         const unsigned short* __restrict__ Ein,
                         unsigned short* __restrict__ Eout) {
    int lane = threadIdx.x & 63;
    int w = (int)((blockIdx.x * (size_t)blockDim.x + threadIdx.x) >> 6);
    int row = __builtin_amdgcn_readfirstlane(w);
    if (row >= NN) return;
    int idx = row + (row >> BSH);
    int beg = rp[idx];
    int end = rp[idx + 1];
    float acc = row_dot(ep, beg, end, Ein, lane);
    __builtin_nontemporal_store(f2bf(acc), &Eout[(size_t)row * DIM + lane]);
}

// ---------------- layer 3: SpMM only at the 2*BATCH target rows, fused acc ----------------
__global__ void spmm_target(const int* __restrict__ rp, const int2* __restrict__ ep,
                            const unsigned short* __restrict__ Ein,
                            const int* __restrict__ U, const int* __restrict__ I,
                            float* __restrict__ accU, float* __restrict__ accI) {
    int lane = threadIdx.x & 63;
    int w = (int)((blockIdx.x * (size_t)blockDim.x + threadIdx.x) >> 6);
    if (w >= 2 * BATCH) return;
    int row;
    float* accp;
    if (w < BATCH) { row = U[w];                   accp = accU + (size_t)w * DIM; }
    else           { row = N_USERS + I[w - BATCH]; accp = accI + (size_t)(w - BATCH) * DIM; }
    row = __builtin_amdgcn_readfirstlane(row);
    int idx = row + (row >> BSH);
    int beg = rp[idx];
    int end = rp[idx + 1];
    float acc = row_dot(ep, beg, end, Ein, lane);
    accp[lane] += acc;
}

// ---------------- acc at the 2*BATCH target rows ----------------
__global__ void acc_init(const float* __restrict__ ue, const float* __restrict__ ie,
                         const int* __restrict__ U, const int* __restrict__ I,
                         float* __restrict__ accU, float* __restrict__ accI) {
    int t = blockIdx.x * blockDim.x + threadIdx.x;
    int b = t >> 6, d = t & 63;
    accU[t] = ue[(size_t)U[b] * DIM + d];
    accI[t] = ie[(size_t)I[b] * DIM + d];
}

__global__ void acc_add(const unsigned short* __restrict__ E, const int* __restrict__ U,
                        const int* __restrict__ I, float* __restrict__ accU,
                        float* __restrict__ accI) {
    int t = blockIdx.x * blockDim.x + threadIdx.x;
    int b = t >> 6, d = t & 63;
    accU[t] += bf2f(E[(size_t)U[b] * DIM + d]);
    accI[t] += bf2f(E[(size_t)(N_USERS + I[b]) * DIM + d]);
}

// ---------------- final: out[b] = dot(accU[b], accI[b]) / 16 ----------------
__global__ void dot_out(const float* __restrict__ accU, const float* __restrict__ accI,
                        float* __restrict__ out) {
    int t = blockIdx.x * blockDim.x + threadIdx.x;
    int b = t >> 6, lane = threadIdx.x & 63;
    float p = accU[t] * accI[t];
    #pragma unroll
    for (int off = 32; off; off >>= 1) p += __shfl_xor(p, off, 64);
    if (lane == 0) out[b] = p * (1.0f / 16.0f);
}

extern "C" void kernel_launch(void* const* d_in, const int* in_sizes, int n_in,
                              void* d_out, int out_size, void* d_ws, size_t ws_size,
                              hipStream_t stream) {
    const float* ue   = (const float*)d_in[0];
    const float* ie   = (const float*)d_in[1];
    const float* vals = (const float*)d_in[2];
    const int*   rows = (const int*)d_in[3];
    const int*   cols = (const int*)d_in[4];
    const int*   U    = (const int*)d_in[5];
    const int*   I    = (const int*)d_in[6];
    float* out = (float*)d_out;

    char* ws = (char*)d_ws;
    const size_t EPbytes = (size_t)NBK * CAP * sizeof(int2);          // 81.6 MB (CAP-strided)
    const size_t EBbytes = (size_t)NN * DIM * sizeof(unsigned short); // 38.4 MB
    const size_t ACbytes = (size_t)BATCH * DIM * sizeof(float);       // 4.2 MB
    const size_t RPbytes = ((size_t)(NN + NBK + 1) * sizeof(int) + 255) & ~(size_t)255;
    const size_t NBbytes = (((size_t)(NBK + 1) * sizeof(int)) + 255) & ~(size_t)255;

    size_t off = 0;
    int2*  epack  = (int2*)(ws + off);                   off += EPbytes;
    char*  region2 = ws + off;                           off += EPbytes; // estage | Ebf_a+Ebf_b
    float* accU   = (float*)(ws + off); off += ACbytes;
    float* accI   = (float*)(ws + off); off += ACbytes;
    int*   rp     = (int*)(ws + off);   off += RPbytes;
    int*   gfill  = (int*)(ws + off);   off += NBbytes;

    // estage (build phase) aliases the Ebf region (layer phase) — disjoint lifetimes
    int2* estage = (int2*)region2;
    unsigned short* Ebf_a = (unsigned short*)region2;
    unsigned short* Ebf_b = (unsigned short*)(region2 + EBbytes);

    const int nBinBlocks = (N_EDGES + CHUNK2 - 1) / CHUNK2;           // 2344

    // --- build CSR (fixed-capacity 512-row buckets) ---
    hipMemsetAsync(gfill, 0, (size_t)(NBK + 1) * sizeof(int), stream);
    bin_sort<<<nBinBlocks, 256, 0, stream>>>(rows, cols, vals, gfill, estage);
    row_scatter<<<NBK, 1024, 0, stream>>>(gfill, estage, epack, rp);

    // --- bf16 embedding table (after estage is dead) + exact-f32 E0 term ---
    to_bf16<<<2048, 256, 0, stream>>>(ue, ie, Ebf_a);
    acc_init<<<BATCH * DIM / 256, 256, 0, stream>>>(ue, ie, U, I, accU, accI);

    const int spmmBlocks = (NN * 64 + 255) / 256;                     // 1 wave per row

    // layer 1: Ebf_a -> Ebf_b
    spmm_csr<<<spmmBlocks, 256, 0, stream>>>(rp, epack, Ebf_a, Ebf_b);
    acc_add<<<BATCH * DIM / 256, 256, 0, stream>>>(Ebf_b, U, I, accU, accI);

    // layer 2: Ebf_b -> Ebf_a
    spmm_csr<<<spmmBlocks, 256, 0, stream>>>(rp, epack, Ebf_b, Ebf_a);
    acc_add<<<BATCH * DIM / 256, 256, 0, stream>>>(Ebf_a, U, I, accU, accI);

    // layer 3: only at target rows, fused accumulate
    spmm_target<<<2 * BATCH * 64 / 256, 256, 0, stream>>>(rp, epack, Ebf_a, U, I, accU, accI);

    dot_out<<<BATCH / 4, 256, 0, stream>>>(accU, accI, out);
}